// Round 17
// baseline (57.763 us; speedup 1.0000x reference)
//
#include <hip/hip_runtime.h>

#define HID 768
#define NL  17
#define BB  64
#define TT  512

// ---- CRF scan geometry (unchanged from R12) ----
#define SEG  16
#define SLEN 32
#define QST  352

typedef __attribute__((ext_vector_type(8))) short bf16x8;
typedef __attribute__((ext_vector_type(4))) float f32x4;

// v_cvt_pk_bf16_f32: dst.lo16 = bf16(a) RNE, dst.hi16 = bf16(b)
__device__ __forceinline__ unsigned cvtpk(float a, float b) {
    unsigned r;
    asm("v_cvt_pk_bf16_f32 %0, %1, %2" : "=v"(r) : "v"(a), "v"(b));
    return r;
}

// ===========================================================================
// Kernel 1: emissions = outputs @ fc_w^T + fc_b   (32768x768 @ 768^T x 17)
// R16 post-mortem: all pipes (HBM 15us, L1 2.6, LDS 3.8, VALU 2) say ~17us;
// measured ~50 -> un-hidden latency, and the 56KB palette capped us at
// 8 waves/CU. Fix: K-PHASE SPLIT palette — stage K[0,384) in 28.2KB, compute
// 12 steps, restage K[384,768), compute 12 — LDS 28.2KB -> 5 blocks/CU =
// 20 waves/CU (2.5x interleave). Rotation/MFMA/layouts unchanged from R16
// (verified): 4-deep named-register x rotation (6KB/wave in flight), MFMA
// split-precision (x~xh+xl bf16; acc = xh.wh+xh.wl+xl.wh, err ~2^-16).
// Palette row stride 392 shorts = 2-way bank alias (free, m136).
// ===========================================================================
__global__ __launch_bounds__(256) void emis_kernel(const float* __restrict__ x,
                                                   const float* __restrict__ w,
                                                   const float* __restrict__ bias,
                                                   float* __restrict__ y) {
    __shared__ unsigned short WP[2][18][392];   // [hi/lo][col (17=zeros)][k%384]

    const int tid = threadIdx.x;

    // stage one K-half of w as bf16 hi/lo palette (1632 float4 granules)
#define PSTAGE(p)                                                             \
    {                                                                         \
        _Pragma("unroll")                                                     \
        for (int j = 0; j < 7; ++j) {                                         \
            const int g4 = tid + 256 * j;                                     \
            if (g4 < 1632) {                                                  \
                const int col = g4 / 96;                                      \
                const int e   = (g4 - col * 96) * 4;                          \
                const float4 f = *reinterpret_cast<const float4*>(            \
                    w + col * HID + 384 * (p) + e);                           \
                const unsigned h0 = cvtpk(f.x, f.y);                          \
                const unsigned h1 = cvtpk(f.z, f.w);                          \
                const unsigned l0 = cvtpk(f.x - __uint_as_float(h0 << 16),    \
                                          f.y - __uint_as_float(h0 & 0xFFFF0000u)); \
                const unsigned l1 = cvtpk(f.z - __uint_as_float(h1 << 16),    \
                                          f.w - __uint_as_float(h1 & 0xFFFF0000u)); \
                uint2 hv; hv.x = h0; hv.y = h1;                               \
                uint2 lv; lv.x = l0; lv.y = l1;                               \
                *reinterpret_cast<uint2*>(&WP[0][col][e]) = hv;               \
                *reinterpret_cast<uint2*>(&WP[1][col][e]) = lv;               \
            }                                                                 \
        }                                                                     \
    }

    for (int e = tid; e < 392; e += 256) { WP[0][17][e] = 0; WP[1][17][e] = 0; }
    PSTAGE(0)
    __syncthreads();

    const int lane = tid & 63;
    const int c0   = lane & 15;                 // A row / B col / D col
    int c1 = 16 + c0; if (c1 > 17) c1 = 17;     // n-tile 1 col (>=17 -> zeros)
    const int kg   = (lane >> 4) * 8;           // k-group offset
    const int mtile = blockIdx.x * 4 + (tid >> 6);
    const float* xp = x + (size_t)(mtile * 16 + c0) * HID + kg;

    const unsigned short* pH0 = &WP[0][c0][kg];
    const unsigned short* pH1 = &WP[0][c1][kg];
    const unsigned short* pL0 = &WP[1][c0][kg];
    const unsigned short* pL1 = &WP[1][c1][kg];

    f32x4 acc0 = {0.f, 0.f, 0.f, 0.f};
    f32x4 acc1 = {0.f, 0.f, 0.f, 0.f};

#define LDX(T)  (*reinterpret_cast<const float4*>(xp + 32 * (T)))
#define LDX4(T) (*reinterpret_cast<const float4*>(xp + 32 * (T) + 4))

#define XSTEP(Q0, Q1, T)                                                      \
    {                                                                         \
        const int LK = 32 * ((T) % 12);        /* palette-local k offset */   \
        union { unsigned u[4]; bf16x8 v; } H_, L_;                            \
        H_.u[0] = cvtpk(Q0.x, Q0.y);                                          \
        H_.u[1] = cvtpk(Q0.z, Q0.w);                                          \
        H_.u[2] = cvtpk(Q1.x, Q1.y);                                          \
        H_.u[3] = cvtpk(Q1.z, Q1.w);                                          \
        L_.u[0] = cvtpk(Q0.x - __uint_as_float(H_.u[0] << 16),                \
                        Q0.y - __uint_as_float(H_.u[0] & 0xFFFF0000u));       \
        L_.u[1] = cvtpk(Q0.z - __uint_as_float(H_.u[1] << 16),                \
                        Q0.w - __uint_as_float(H_.u[1] & 0xFFFF0000u));       \
        L_.u[2] = cvtpk(Q1.x - __uint_as_float(H_.u[2] << 16),                \
                        Q1.y - __uint_as_float(H_.u[2] & 0xFFFF0000u));       \
        L_.u[3] = cvtpk(Q1.z - __uint_as_float(H_.u[3] << 16),                \
                        Q1.w - __uint_as_float(H_.u[3] & 0xFFFF0000u));       \
        const bf16x8 bh0 = *reinterpret_cast<const bf16x8*>(pH0 + LK);        \
        const bf16x8 bh1 = *reinterpret_cast<const bf16x8*>(pH1 + LK);        \
        const bf16x8 bl0 = *reinterpret_cast<const bf16x8*>(pL0 + LK);        \
        const bf16x8 bl1 = *reinterpret_cast<const bf16x8*>(pL1 + LK);        \
        acc0 = __builtin_amdgcn_mfma_f32_16x16x32_bf16(H_.v, bh0, acc0, 0, 0, 0); \
        acc0 = __builtin_amdgcn_mfma_f32_16x16x32_bf16(H_.v, bl0, acc0, 0, 0, 0); \
        acc0 = __builtin_amdgcn_mfma_f32_16x16x32_bf16(L_.v, bh0, acc0, 0, 0, 0); \
        acc1 = __builtin_amdgcn_mfma_f32_16x16x32_bf16(H_.v, bh1, acc1, 0, 0, 0); \
        acc1 = __builtin_amdgcn_mfma_f32_16x16x32_bf16(H_.v, bl1, acc1, 0, 0, 0); \
        acc1 = __builtin_amdgcn_mfma_f32_16x16x32_bf16(L_.v, bh1, acc1, 0, 0, 0); \
    }

#define ITER(T)                                                               \
    XSTEP(qA0, qA1, (T))                                                      \
    if ((T) + 4 < 24) { qA0 = LDX((T) + 4); qA1 = LDX4((T) + 4); }            \
    XSTEP(qB0, qB1, (T) + 1)                                                  \
    if ((T) + 5 < 24) { qB0 = LDX((T) + 5); qB1 = LDX4((T) + 5); }            \
    XSTEP(qC0, qC1, (T) + 2)                                                  \
    if ((T) + 6 < 24) { qC0 = LDX((T) + 6); qC1 = LDX4((T) + 6); }            \
    XSTEP(qD0, qD1, (T) + 3)                                                  \
    if ((T) + 7 < 24) { qD0 = LDX((T) + 7); qD1 = LDX4((T) + 7); }

    // 4-deep rotation: qA..qD named pairs, 6KB/wave in flight at every stall
    float4 qA0 = LDX(0), qA1 = LDX4(0);
    float4 qB0 = LDX(1), qB1 = LDX4(1);
    float4 qC0 = LDX(2), qC1 = LDX4(2);
    float4 qD0 = LDX(3), qD1 = LDX4(3);

    // ---- phase 0: K steps 0..11 ----
    ITER(0) ITER(4) ITER(8)

    // ---- restage palette for K[384,768) ----
    __syncthreads();                            // all waves done reading phase 0
    PSTAGE(1)
    __syncthreads();                            // phase 1 palette ready

    // ---- phase 1: K steps 12..23 ----
    ITER(12) ITER(16) ITER(20)

#undef ITER
#undef XSTEP
#undef LDX
#undef LDX4
#undef PSTAGE

    // ---- epilogue: D col = lane&15, row = (lane>>4)*4 + i ----
    const float bc  = bias[c0];
    const float b16 = bias[16];
    const int   rb  = mtile * 16 + (lane >> 4) * 4;
#pragma unroll
    for (int i = 0; i < 4; ++i) {
        const int row = rb + i;
        y[(size_t)row * NL + c0] = acc0[i] + bc;                // cols 0..15
        if (c0 == 0) y[(size_t)row * NL + 16] = acc1[i] + b16;  // col 16
    }
}

// ===========================================================================
// Kernel 2a: CRF segment scan — UNCHANGED from R12.
// ===========================================================================
__global__ __launch_bounds__(64) void crf_scan_kernel(const float* __restrict__ emis,
                                                      const float* __restrict__ tr_,
                                                      const int* __restrict__ mask,
                                                      float* __restrict__ ws) {
    __shared__ float QT[2][18][20];

    const int bs = blockIdx.x;
    const int b  = bs >> 4;
    const int s  = bs & 15;
    const int l  = threadIdx.x;
    const float* eb = emis + (size_t)b * TT * NL;

    int lenp = 0;
#pragma unroll
    for (int m = 0; m < 8; ++m) lenp += (mask[b * TT + l + 64 * m] != 0);
#pragma unroll
    for (int off = 32; off; off >>= 1) lenp += __shfl_down(lenp, off);
    const int len = __shfl(lenp, 0);

    const int t0    = 1 + SLEN * s;
    const int tend  = min(t0 + SLEN, len);
    const int trips = (tend > t0) ? (tend - t0) : 0;

    const bool act = (l < 51);
    const int  i   = act ? (l / 3) : 0;
    const int  m   = act ? (l - 3 * (l / 3)) : 0;
    const int  j0  = 6 * m;

    if (act) {
#pragma unroll
        for (int jj = 0; jj < 6; ++jj)
            QT[0][j0 + jj][i] = (i == j0 + jj) ? 1.f : 0.f;
    }

    float at[17];
#pragma unroll
    for (int k = 0; k < 17; ++k) at[k] = __expf(tr_[k * NL + i]);

    float psc = 1.f;
    int   Mi  = 0;
    float emv = (trips > 0) ? eb[t0 * NL + i] : 0.f;
    int   t   = t0;

#define QSTEP(SRC, DST, TCUR)                                                 \
    {                                                                         \
        const float e_ = __expf(emv) * psc;  psc = 1.f;                       \
        const int tn_ = ((TCUR) + 1 < tend) ? ((TCUR) + 1) : (TT - 1);        \
        const float env_ = eb[tn_ * NL + i];                                  \
        float o[6];                                                           \
        _Pragma("unroll")                                                     \
        for (int jj = 0; jj < 6; ++jj) {                                      \
            const float* qr = &QT[SRC][j0 + jj][0];                           \
            const float4 a0 = *reinterpret_cast<const float4*>(qr);           \
            const float4 a1 = *reinterpret_cast<const float4*>(qr + 4);       \
            const float4 a2 = *reinterpret_cast<const float4*>(qr + 8);       \
            const float4 a3 = *reinterpret_cast<const float4*>(qr + 12);      \
            const float aL  = qr[16];                                         \
            float u0 = at[0] * a0.x, u1 = at[1] * a0.y;                       \
            float u2 = at[2] * a0.z, u3 = at[3] * a0.w;                       \
            u0 = fmaf(at[4],  a1.x, u0); u1 = fmaf(at[5],  a1.y, u1);         \
            u2 = fmaf(at[6],  a1.z, u2); u3 = fmaf(at[7],  a1.w, u3);         \
            u0 = fmaf(at[8],  a2.x, u0); u1 = fmaf(at[9],  a2.y, u1);         \
            u2 = fmaf(at[10], a2.z, u2); u3 = fmaf(at[11], a2.w, u3);         \
            u0 = fmaf(at[12], a3.x, u0); u1 = fmaf(at[13], a3.y, u1);         \
            u2 = fmaf(at[14], a3.z, u2); u3 = fmaf(at[15], a3.w, u3);         \
            u0 = fmaf(at[16], aL,   u0);                                      \
            o[jj] = (u0 + u1) + (u2 + u3);                                    \
        }                                                                     \
        if (act) {                                                            \
            _Pragma("unroll")                                                 \
            for (int jj = 0; jj < 6; ++jj)                                    \
                QT[DST][j0 + jj][i] = e_ * o[jj];                             \
        }                                                                     \
        emv = env_;                                                           \
    }

    for (int pp = 0; pp < (trips >> 1); ++pp) {
        QSTEP(0, 1, t)
        QSTEP(1, 0, t + 1)
        t += 2;
        const float q00 = QT[0][0][0];
        const int E = (int)((__float_as_uint(q00) >> 23) & 0xff) - 127;
        Mi += E;
        psc = __builtin_amdgcn_ldexpf(1.f, -E);
    }
    int sbuf = 0;
    if (trips & 1) { QSTEP(0, 1, t) sbuf = 1; }
#undef QSTEP

    if (act) {
        float* dst = ws + (size_t)bs * QST + i * 20;
#pragma unroll
        for (int jj = 0; jj < 6; ++jj) {
            const int j = j0 + jj;
            if (j < 17) dst[j] = psc * QT[sbuf][j][i];
        }
    }
    if (l == 0) ws[(size_t)bs * QST + 340] = (float)Mi;
}

// ===========================================================================
// Kernel 2b: combine — UNCHANGED from R12.
// ===========================================================================
__device__ __forceinline__ float bcast(float v, int i) {
    return __uint_as_float(__builtin_amdgcn_readlane(__float_as_uint(v), i));
}

__global__ __launch_bounds__(64) void crf_combine_kernel(const float* __restrict__ emis,
                                                         const float* __restrict__ st_,
                                                         const float* __restrict__ en_,
                                                         const float* __restrict__ tr_,
                                                         const int* __restrict__ labels,
                                                         const int* __restrict__ mask,
                                                         const float* __restrict__ ws,
                                                         float* __restrict__ llh) {
    const int b = blockIdx.x;
    const int l = threadIdx.x;
    const float* eb = emis + (size_t)b * TT * NL;
    const int*   lb = labels + b * TT;

    int lenp = 0;
#pragma unroll
    for (int m = 0; m < 8; ++m) lenp += (mask[b * TT + l + 64 * m] != 0);
#pragma unroll
    for (int off = 32; off; off >>= 1) lenp += __shfl_down(lenp, off);
    const int len = __shfl(lenp, 0);

    float np = 0.f;
#pragma unroll
    for (int m = 0; m < 8; ++m) {
        const int t = l + 64 * m;
        int tag = lb[t]; if ((unsigned)tag >= NL) tag = 0;
        if (t < len) {
            if (t == 0) {
                np += st_[tag] + eb[tag];
            } else {
                int tp = lb[t - 1]; if ((unsigned)tp >= NL) tp = 0;
                np += tr_[tp * NL + tag] + eb[t * NL + tag];
            }
            if (t == len - 1) np += en_[tag];
        }
    }
#pragma unroll
    for (int off = 32; off; off >>= 1) np += __shfl_down(np, off);
    const float num = __shfl(np, 0);

    const bool act = (l < NL);
    const int  j   = act ? l : 0;

    float p  = act ? __expf(st_[j] + eb[j]) : 0.f;
    int   Mi = 0;

    for (int s = 0; s < SEG; ++s) {
        const float* qs = ws + (size_t)(b * SEG + s) * QST;
        const float* qr = qs + j * 20;
        const float4 a0 = *reinterpret_cast<const float4*>(qr);
        const float4 a1 = *reinterpret_cast<const float4*>(qr + 4);
        const float4 a2 = *reinterpret_cast<const float4*>(qr + 8);
        const float4 a3 = *reinterpret_cast<const float4*>(qr + 12);
        const float  aL = qr[16];
        const float  Msc = qs[340];

        float u0 = a0.x * bcast(p, 0),  u1 = a0.y * bcast(p, 1);
        float u2 = a0.z * bcast(p, 2),  u3 = a0.w * bcast(p, 3);
        u0 = fmaf(a1.x, bcast(p, 4),  u0); u1 = fmaf(a1.y, bcast(p, 5),  u1);
        u2 = fmaf(a1.z, bcast(p, 6),  u2); u3 = fmaf(a1.w, bcast(p, 7),  u3);
        u0 = fmaf(a2.x, bcast(p, 8),  u0); u1 = fmaf(a2.y, bcast(p, 9),  u1);
        u2 = fmaf(a2.z, bcast(p, 10), u2); u3 = fmaf(a2.w, bcast(p, 11), u3);
        u0 = fmaf(a3.x, bcast(p, 12), u0); u1 = fmaf(a3.y, bcast(p, 13), u1);
        u2 = fmaf(a3.z, bcast(p, 14), u2); u3 = fmaf(a3.w, bcast(p, 15), u3);
        u0 = fmaf(aL,   bcast(p, 16), u0);
        p = act ? ((u0 + u1) + (u2 + u3)) : 0.f;
        Mi += (int)Msc;

        const unsigned pb = (unsigned)__builtin_amdgcn_readlane((int)__float_as_uint(p), 0);
        const int e = (int)((pb >> 23) & 0xff) - 127;
        Mi += e;
        p = __builtin_amdgcn_ldexpf(p, -e);
    }

    float v = act ? p * __expf(en_[j]) : 0.f;
#pragma unroll
    for (int off = 32; off; off >>= 1) v += __shfl_down(v, off);

    if (l == 0) {
        const float denom = (float)Mi * 0.6931471805599453f + __logf(v);
        llh[b] = num - denom;
    }
}

// ===========================================================================
// Kernel 3: loss = -mean(llh)
// ===========================================================================
__global__ __launch_bounds__(64) void loss_kernel(const float* __restrict__ llh,
                                                  float* __restrict__ loss) {
    float v = llh[threadIdx.x];
#pragma unroll
    for (int off = 32; off; off >>= 1) v += __shfl_down(v, off);
    if (threadIdx.x == 0) loss[0] = -(v * (1.0f / BB));
}

// ===========================================================================
extern "C" void kernel_launch(void* const* d_in, const int* in_sizes, int n_in,
                              void* d_out, int out_size, void* d_ws, size_t ws_size,
                              hipStream_t stream) {
    const float* outputs = (const float*)d_in[0];
    const float* fc_w    = (const float*)d_in[1];
    const float* fc_b    = (const float*)d_in[2];
    const float* start_t = (const float*)d_in[3];
    const float* end_t   = (const float*)d_in[4];
    const float* trans   = (const float*)d_in[5];
    const int*   labels  = (const int*)d_in[6];
    const int*   mask    = (const int*)d_in[7];

    float* emis = (float*)d_out;
    float* loss = emis + (size_t)BB * TT * NL;
    float* ws   = (float*)d_ws;
    float* llh  = ws + (size_t)BB * SEG * QST;

    emis_kernel<<<(BB * TT) / 64, 256, 0, stream>>>(outputs, fc_w, fc_b, emis);
    crf_scan_kernel<<<BB * SEG, 64, 0, stream>>>(emis, trans, mask, ws);
    crf_combine_kernel<<<BB, 64, 0, stream>>>(emis, start_t, end_t, trans,
                                              labels, mask, ws, llh);
    loss_kernel<<<1, 64, 0, stream>>>(llh, loss);
}

// Round 18
// 55.909 us; speedup vs baseline: 1.0332x; 1.0332x over previous
//
#include <hip/hip_runtime.h>

#define HID 768
#define NL  17
#define BB  64
#define TT  512

// ---- CRF scan geometry (unchanged from R12) ----
#define SEG  16
#define SLEN 32
#define QST  352

typedef __attribute__((ext_vector_type(8))) short bf16x8;
typedef __attribute__((ext_vector_type(4))) float f32x4;

// v_cvt_pk_bf16_f32: dst.lo16 = bf16(a) RNE, dst.hi16 = bf16(b)
__device__ __forceinline__ unsigned cvtpk(float a, float b) {
    unsigned r;
    asm("v_cvt_pk_bf16_f32 %0, %1, %2" : "=v"(r) : "v"(a), "v"(b));
    return r;
}

// ===========================================================================
// Kernel 1: emissions = outputs @ fc_w^T + fc_b   (32768x768 @ 768^T x 17)
// R17 post-mortem: occupancy 2.5x'd -> no change; NaN-pass replays show 60us
// even with ALL data L2/L3-cached (2.2MB HBM). Every pipe models <=3us. The
// untested invariant: ALL variants sweep K in LOCKSTEP with 3072B row stride
// -> at any instant the whole chip requests addr = row*3072 + phi*128 for
// the same phi -> only a subset of HBM channels / L3 slices hit (stride-3072
// interleave aliasing), ~2TB/s wall; congiested-channel vmcnt stalls keep
// waves phase-locked. m13-copy/fillBuffer cover channels uniformly -> 6-7TB/s.
// FIX: de-phase K — each wave starts its 24-step K sweep at roff =
// (blockIdx + 6*wid) % 24 (accumulation order-independent). Everything else
// = R16 verified structure: full 56KB bf16 hi/lo w palette, 4-deep named-
// register x rotation, MFMA split-precision (err ~2^-16).
// ===========================================================================
__global__ __launch_bounds__(256) void emis_kernel(const float* __restrict__ x,
                                                   const float* __restrict__ w,
                                                   const float* __restrict__ bias,
                                                   float* __restrict__ y) {
    __shared__ unsigned short WP[2][18][776];   // [hi/lo][col (17=zeros)][k]

    const int tid = threadIdx.x;

    // ---- stage w as bf16 hi/lo palette (once per block) ----
    for (int e = tid; e < 776; e += 256) { WP[0][17][e] = 0; WP[1][17][e] = 0; }
#pragma unroll
    for (int j = 0; j < 13; ++j) {
        const int g4 = tid + 256 * j;           // float4 granule 0..3263
        if (g4 < 3264) {
            const float4 f = *reinterpret_cast<const float4*>(w + 4 * g4);
            const int col = g4 / 192;           // 192 granules per row
            const int e   = (g4 - col * 192) * 4;
            const unsigned h0 = cvtpk(f.x, f.y);
            const unsigned h1 = cvtpk(f.z, f.w);
            const unsigned l0 = cvtpk(f.x - __uint_as_float(h0 << 16),
                                      f.y - __uint_as_float(h0 & 0xFFFF0000u));
            const unsigned l1 = cvtpk(f.z - __uint_as_float(h1 << 16),
                                      f.w - __uint_as_float(h1 & 0xFFFF0000u));
            uint2 hv; hv.x = h0; hv.y = h1;
            uint2 lv; lv.x = l0; lv.y = l1;
            *reinterpret_cast<uint2*>(&WP[0][col][e]) = hv;
            *reinterpret_cast<uint2*>(&WP[1][col][e]) = lv;
        }
    }
    __syncthreads();

    const int lane = tid & 63;
    const int c0   = lane & 15;                 // A row / B col / D col
    int c1 = 16 + c0; if (c1 > 17) c1 = 17;     // n-tile 1 col (>=17 -> zeros)
    const int kg   = (lane >> 4) * 8;           // k-group offset
    const int mtile = blockIdx.x * 4 + (tid >> 6);
    const float* xp = x + (size_t)(mtile * 16 + c0) * HID + kg;

    // K de-phase: wave-uniform rotation of the 24-step sweep
    const int roff = (blockIdx.x + 6 * (tid >> 6)) % 24;

    const unsigned short* pH0 = &WP[0][c0][kg];
    const unsigned short* pH1 = &WP[0][c1][kg];
    const unsigned short* pL0 = &WP[1][c0][kg];
    const unsigned short* pL1 = &WP[1][c1][kg];

    f32x4 acc0 = {0.f, 0.f, 0.f, 0.f};
    f32x4 acc1 = {0.f, 0.f, 0.f, 0.f};

#define TE(T)   ((T) + roff < 24 ? (T) + roff : (T) + roff - 24)
#define LDX(T)  (*reinterpret_cast<const float4*>(xp + 32 * TE(T)))
#define LDX4(T) (*reinterpret_cast<const float4*>(xp + 32 * TE(T) + 4))

#define XSTEP(Q0, Q1, T)                                                      \
    {                                                                         \
        const int LK = 32 * TE(T);              /* palette k offset */        \
        union { unsigned u[4]; bf16x8 v; } H_, L_;                            \
        H_.u[0] = cvtpk(Q0.x, Q0.y);                                          \
        H_.u[1] = cvtpk(Q0.z, Q0.w);                                          \
        H_.u[2] = cvtpk(Q1.x, Q1.y);                                          \
        H_.u[3] = cvtpk(Q1.z, Q1.w);                                          \
        L_.u[0] = cvtpk(Q0.x - __uint_as_float(H_.u[0] << 16),                \
                        Q0.y - __uint_as_float(H_.u[0] & 0xFFFF0000u));       \
        L_.u[1] = cvtpk(Q0.z - __uint_as_float(H_.u[1] << 16),                \
                        Q0.w - __uint_as_float(H_.u[1] & 0xFFFF0000u));       \
        L_.u[2] = cvtpk(Q1.x - __uint_as_float(H_.u[2] << 16),                \
                        Q1.y - __uint_as_float(H_.u[2] & 0xFFFF0000u));       \
        L_.u[3] = cvtpk(Q1.z - __uint_as_float(H_.u[3] << 16),                \
                        Q1.w - __uint_as_float(H_.u[3] & 0xFFFF0000u));       \
        const bf16x8 bh0 = *reinterpret_cast<const bf16x8*>(pH0 + LK);        \
        const bf16x8 bh1 = *reinterpret_cast<const bf16x8*>(pH1 + LK);        \
        const bf16x8 bl0 = *reinterpret_cast<const bf16x8*>(pL0 + LK);        \
        const bf16x8 bl1 = *reinterpret_cast<const bf16x8*>(pL1 + LK);        \
        acc0 = __builtin_amdgcn_mfma_f32_16x16x32_bf16(H_.v, bh0, acc0, 0, 0, 0); \
        acc0 = __builtin_amdgcn_mfma_f32_16x16x32_bf16(H_.v, bl0, acc0, 0, 0, 0); \
        acc0 = __builtin_amdgcn_mfma_f32_16x16x32_bf16(L_.v, bh0, acc0, 0, 0, 0); \
        acc1 = __builtin_amdgcn_mfma_f32_16x16x32_bf16(H_.v, bh1, acc1, 0, 0, 0); \
        acc1 = __builtin_amdgcn_mfma_f32_16x16x32_bf16(H_.v, bl1, acc1, 0, 0, 0); \
        acc1 = __builtin_amdgcn_mfma_f32_16x16x32_bf16(L_.v, bh1, acc1, 0, 0, 0); \
    }

    // 4-deep rotation: qA..qD named pairs, 6KB/wave in flight at every stall
    float4 qA0 = LDX(0), qA1 = LDX4(0);
    float4 qB0 = LDX(1), qB1 = LDX4(1);
    float4 qC0 = LDX(2), qC1 = LDX4(2);
    float4 qD0 = LDX(3), qD1 = LDX4(3);

#pragma unroll
    for (int t = 0; t < 24; t += 4) {
        XSTEP(qA0, qA1, t)
        if (t + 4 < 24) { qA0 = LDX(t + 4); qA1 = LDX4(t + 4); }
        XSTEP(qB0, qB1, t + 1)
        if (t + 5 < 24) { qB0 = LDX(t + 5); qB1 = LDX4(t + 5); }
        XSTEP(qC0, qC1, t + 2)
        if (t + 6 < 24) { qC0 = LDX(t + 6); qC1 = LDX4(t + 6); }
        XSTEP(qD0, qD1, t + 3)
        if (t + 7 < 24) { qD0 = LDX(t + 7); qD1 = LDX4(t + 7); }
    }
#undef XSTEP
#undef LDX
#undef LDX4
#undef TE

    // ---- epilogue: D col = lane&15, row = (lane>>4)*4 + i ----
    const float bc  = bias[c0];
    const float b16 = bias[16];
    const int   rb  = mtile * 16 + (lane >> 4) * 4;
#pragma unroll
    for (int i = 0; i < 4; ++i) {
        const int row = rb + i;
        y[(size_t)row * NL + c0] = acc0[i] + bc;                // cols 0..15
        if (c0 == 0) y[(size_t)row * NL + 16] = acc1[i] + b16;  // col 16
    }
}

// ===========================================================================
// Kernel 2a: CRF segment scan — UNCHANGED from R12.
// ===========================================================================
__global__ __launch_bounds__(64) void crf_scan_kernel(const float* __restrict__ emis,
                                                      const float* __restrict__ tr_,
                                                      const int* __restrict__ mask,
                                                      float* __restrict__ ws) {
    __shared__ float QT[2][18][20];

    const int bs = blockIdx.x;
    const int b  = bs >> 4;
    const int s  = bs & 15;
    const int l  = threadIdx.x;
    const float* eb = emis + (size_t)b * TT * NL;

    int lenp = 0;
#pragma unroll
    for (int m = 0; m < 8; ++m) lenp += (mask[b * TT + l + 64 * m] != 0);
#pragma unroll
    for (int off = 32; off; off >>= 1) lenp += __shfl_down(lenp, off);
    const int len = __shfl(lenp, 0);

    const int t0    = 1 + SLEN * s;
    const int tend  = min(t0 + SLEN, len);
    const int trips = (tend > t0) ? (tend - t0) : 0;

    const bool act = (l < 51);
    const int  i   = act ? (l / 3) : 0;
    const int  m   = act ? (l - 3 * (l / 3)) : 0;
    const int  j0  = 6 * m;

    if (act) {
#pragma unroll
        for (int jj = 0; jj < 6; ++jj)
            QT[0][j0 + jj][i] = (i == j0 + jj) ? 1.f : 0.f;
    }

    float at[17];
#pragma unroll
    for (int k = 0; k < 17; ++k) at[k] = __expf(tr_[k * NL + i]);

    float psc = 1.f;
    int   Mi  = 0;
    float emv = (trips > 0) ? eb[t0 * NL + i] : 0.f;
    int   t   = t0;

#define QSTEP(SRC, DST, TCUR)                                                 \
    {                                                                         \
        const float e_ = __expf(emv) * psc;  psc = 1.f;                       \
        const int tn_ = ((TCUR) + 1 < tend) ? ((TCUR) + 1) : (TT - 1);        \
        const float env_ = eb[tn_ * NL + i];                                  \
        float o[6];                                                           \
        _Pragma("unroll")                                                     \
        for (int jj = 0; jj < 6; ++jj) {                                      \
            const float* qr = &QT[SRC][j0 + jj][0];                           \
            const float4 a0 = *reinterpret_cast<const float4*>(qr);           \
            const float4 a1 = *reinterpret_cast<const float4*>(qr + 4);       \
            const float4 a2 = *reinterpret_cast<const float4*>(qr + 8);       \
            const float4 a3 = *reinterpret_cast<const float4*>(qr + 12);      \
            const float aL  = qr[16];                                         \
            float u0 = at[0] * a0.x, u1 = at[1] * a0.y;                       \
            float u2 = at[2] * a0.z, u3 = at[3] * a0.w;                       \
            u0 = fmaf(at[4],  a1.x, u0); u1 = fmaf(at[5],  a1.y, u1);         \
            u2 = fmaf(at[6],  a1.z, u2); u3 = fmaf(at[7],  a1.w, u3);         \
            u0 = fmaf(at[8],  a2.x, u0); u1 = fmaf(at[9],  a2.y, u1);         \
            u2 = fmaf(at[10], a2.z, u2); u3 = fmaf(at[11], a2.w, u3);         \
            u0 = fmaf(at[12], a3.x, u0); u1 = fmaf(at[13], a3.y, u1);         \
            u2 = fmaf(at[14], a3.z, u2); u3 = fmaf(at[15], a3.w, u3);         \
            u0 = fmaf(at[16], aL,   u0);                                      \
            o[jj] = (u0 + u1) + (u2 + u3);                                    \
        }                                                                     \
        if (act) {                                                            \
            _Pragma("unroll")                                                 \
            for (int jj = 0; jj < 6; ++jj)                                    \
                QT[DST][j0 + jj][i] = e_ * o[jj];                             \
        }                                                                     \
        emv = env_;                                                           \
    }

    for (int pp = 0; pp < (trips >> 1); ++pp) {
        QSTEP(0, 1, t)
        QSTEP(1, 0, t + 1)
        t += 2;
        const float q00 = QT[0][0][0];
        const int E = (int)((__float_as_uint(q00) >> 23) & 0xff) - 127;
        Mi += E;
        psc = __builtin_amdgcn_ldexpf(1.f, -E);
    }
    int sbuf = 0;
    if (trips & 1) { QSTEP(0, 1, t) sbuf = 1; }
#undef QSTEP

    if (act) {
        float* dst = ws + (size_t)bs * QST + i * 20;
#pragma unroll
        for (int jj = 0; jj < 6; ++jj) {
            const int j = j0 + jj;
            if (j < 17) dst[j] = psc * QT[sbuf][j][i];
        }
    }
    if (l == 0) ws[(size_t)bs * QST + 340] = (float)Mi;
}

// ===========================================================================
// Kernel 2b: combine — UNCHANGED from R12.
// ===========================================================================
__device__ __forceinline__ float bcast(float v, int i) {
    return __uint_as_float(__builtin_amdgcn_readlane(__float_as_uint(v), i));
}

__global__ __launch_bounds__(64) void crf_combine_kernel(const float* __restrict__ emis,
                                                         const float* __restrict__ st_,
                                                         const float* __restrict__ en_,
                                                         const float* __restrict__ tr_,
                                                         const int* __restrict__ labels,
                                                         const int* __restrict__ mask,
                                                         const float* __restrict__ ws,
                                                         float* __restrict__ llh) {
    const int b = blockIdx.x;
    const int l = threadIdx.x;
    const float* eb = emis + (size_t)b * TT * NL;
    const int*   lb = labels + b * TT;

    int lenp = 0;
#pragma unroll
    for (int m = 0; m < 8; ++m) lenp += (mask[b * TT + l + 64 * m] != 0);
#pragma unroll
    for (int off = 32; off; off >>= 1) lenp += __shfl_down(lenp, off);
    const int len = __shfl(lenp, 0);

    float np = 0.f;
#pragma unroll
    for (int m = 0; m < 8; ++m) {
        const int t = l + 64 * m;
        int tag = lb[t]; if ((unsigned)tag >= NL) tag = 0;
        if (t < len) {
            if (t == 0) {
                np += st_[tag] + eb[tag];
            } else {
                int tp = lb[t - 1]; if ((unsigned)tp >= NL) tp = 0;
                np += tr_[tp * NL + tag] + eb[t * NL + tag];
            }
            if (t == len - 1) np += en_[tag];
        }
    }
#pragma unroll
    for (int off = 32; off; off >>= 1) np += __shfl_down(np, off);
    const float num = __shfl(np, 0);

    const bool act = (l < NL);
    const int  j   = act ? l : 0;

    float p  = act ? __expf(st_[j] + eb[j]) : 0.f;
    int   Mi = 0;

    for (int s = 0; s < SEG; ++s) {
        const float* qs = ws + (size_t)(b * SEG + s) * QST;
        const float* qr = qs + j * 20;
        const float4 a0 = *reinterpret_cast<const float4*>(qr);
        const float4 a1 = *reinterpret_cast<const float4*>(qr + 4);
        const float4 a2 = *reinterpret_cast<const float4*>(qr + 8);
        const float4 a3 = *reinterpret_cast<const float4*>(qr + 12);
        const float  aL = qr[16];
        const float  Msc = qs[340];

        float u0 = a0.x * bcast(p, 0),  u1 = a0.y * bcast(p, 1);
        float u2 = a0.z * bcast(p, 2),  u3 = a0.w * bcast(p, 3);
        u0 = fmaf(a1.x, bcast(p, 4),  u0); u1 = fmaf(a1.y, bcast(p, 5),  u1);
        u2 = fmaf(a1.z, bcast(p, 6),  u2); u3 = fmaf(a1.w, bcast(p, 7),  u3);
        u0 = fmaf(a2.x, bcast(p, 8),  u0); u1 = fmaf(a2.y, bcast(p, 9),  u1);
        u2 = fmaf(a2.z, bcast(p, 10), u2); u3 = fmaf(a2.w, bcast(p, 11), u3);
        u0 = fmaf(a3.x, bcast(p, 12), u0); u1 = fmaf(a3.y, bcast(p, 13), u1);
        u2 = fmaf(a3.z, bcast(p, 14), u2); u3 = fmaf(a3.w, bcast(p, 15), u3);
        u0 = fmaf(aL,   bcast(p, 16), u0);
        p = act ? ((u0 + u1) + (u2 + u3)) : 0.f;
        Mi += (int)Msc;

        const unsigned pb = (unsigned)__builtin_amdgcn_readlane((int)__float_as_uint(p), 0);
        const int e = (int)((pb >> 23) & 0xff) - 127;
        Mi += e;
        p = __builtin_amdgcn_ldexpf(p, -e);
    }

    float v = act ? p * __expf(en_[j]) : 0.f;
#pragma unroll
    for (int off = 32; off; off >>= 1) v += __shfl_down(v, off);

    if (l == 0) {
        const float denom = (float)Mi * 0.6931471805599453f + __logf(v);
        llh[b] = num - denom;
    }
}

// ===========================================================================
// Kernel 3: loss = -mean(llh)
// ===========================================================================
__global__ __launch_bounds__(64) void loss_kernel(const float* __restrict__ llh,
                                                  float* __restrict__ loss) {
    float v = llh[threadIdx.x];
#pragma unroll
    for (int off = 32; off; off >>= 1) v += __shfl_down(v, off);
    if (threadIdx.x == 0) loss[0] = -(v * (1.0f / BB));
}

// ===========================================================================
extern "C" void kernel_launch(void* const* d_in, const int* in_sizes, int n_in,
                              void* d_out, int out_size, void* d_ws, size_t ws_size,
                              hipStream_t stream) {
    const float* outputs = (const float*)d_in[0];
    const float* fc_w    = (const float*)d_in[1];
    const float* fc_b    = (const float*)d_in[2];
    const float* start_t = (const float*)d_in[3];
    const float* end_t   = (const float*)d_in[4];
    const float* trans   = (const float*)d_in[5];
    const int*   labels  = (const int*)d_in[6];
    const int*   mask    = (const int*)d_in[7];

    float* emis = (float*)d_out;
    float* loss = emis + (size_t)BB * TT * NL;
    float* ws   = (float*)d_ws;
    float* llh  = ws + (size_t)BB * SEG * QST;

    emis_kernel<<<(BB * TT) / 64, 256, 0, stream>>>(outputs, fc_w, fc_b, emis);
    crf_scan_kernel<<<BB * SEG, 64, 0, stream>>>(emis, trans, mask, ws);
    crf_combine_kernel<<<BB, 64, 0, stream>>>(emis, start_t, end_t, trans,
                                              labels, mask, ws, llh);
    loss_kernel<<<1, 64, 0, stream>>>(llh, loss);
}

// Round 19
// 53.972 us; speedup vs baseline: 1.0702x; 1.0359x over previous
//
#include <hip/hip_runtime.h>

#define HID 768
#define NL  17
#define BB  64
#define TT  512

#define SEG  16
#define SLEN 32
#define QST  352

typedef __attribute__((ext_vector_type(8))) short bf16x8;
typedef __attribute__((ext_vector_type(4))) float f32x4;

// v_cvt_pk_bf16_f32: dst.lo16 = bf16(a) RNE, dst.hi16 = bf16(b)
__device__ __forceinline__ unsigned cvtpk(float a, float b) {
    unsigned r;
    asm("v_cvt_pk_bf16_f32 %0, %1, %2" : "=v"(r) : "v"(a), "v"(b));
    return r;
}

// ===========================================================================
// Kernel 1 (FUSED): emissions GEMM + CRF segment scan.
// Emis part = R16-verified structure (full 56KB bf16 hi/lo w palette, 4-deep
// named-register x rotation, MFMA split-precision, err ~2^-16). After the
// epilogue, emissions for this block's 64 rows (= 2 segments of one batch,
// re-partitioned to t in [32s, 32s+32)) are scattered to LDS and waves 0-1
// run the two 17x17 matrix-product scans in-block — hidden under other
// blocks' emis phases instead of a serial follow-up kernel.
// ===========================================================================
__global__ __launch_bounds__(256) void emis_scan_kernel(const float* __restrict__ x,
                                                        const float* __restrict__ w,
                                                        const float* __restrict__ bias,
                                                        const int* __restrict__ mask,
                                                        const float* __restrict__ tr_,
                                                        float* __restrict__ y,
                                                        float* __restrict__ ws) {
    __shared__ unsigned short WP[2][18][776];   // 55.9 KB palette
    __shared__ float em_s[64][20];              // 5.1 KB  this block's emissions
    __shared__ float QT[2][2][18][20];          // 5.8 KB  per-segment scan state

    const int tid = threadIdx.x;

    // ---- stage w as bf16 hi/lo palette (once per block) ----
    for (int e = tid; e < 776; e += 256) { WP[0][17][e] = 0; WP[1][17][e] = 0; }
#pragma unroll
    for (int j = 0; j < 13; ++j) {
        const int g4 = tid + 256 * j;           // float4 granule 0..3263
        if (g4 < 3264) {
            const float4 f = *reinterpret_cast<const float4*>(w + 4 * g4);
            const int col = g4 / 192;
            const int e   = (g4 - col * 192) * 4;
            const unsigned h0 = cvtpk(f.x, f.y);
            const unsigned h1 = cvtpk(f.z, f.w);
            const unsigned l0 = cvtpk(f.x - __uint_as_float(h0 << 16),
                                      f.y - __uint_as_float(h0 & 0xFFFF0000u));
            const unsigned l1 = cvtpk(f.z - __uint_as_float(h1 << 16),
                                      f.w - __uint_as_float(h1 & 0xFFFF0000u));
            uint2 hv; hv.x = h0; hv.y = h1;
            uint2 lv; lv.x = l0; lv.y = l1;
            *reinterpret_cast<uint2*>(&WP[0][col][e]) = hv;
            *reinterpret_cast<uint2*>(&WP[1][col][e]) = lv;
        }
    }
    __syncthreads();

    const int lane = tid & 63;
    const int c0   = lane & 15;                 // A row / B col / D col
    int c1 = 16 + c0; if (c1 > 17) c1 = 17;     // n-tile 1 col (>=17 -> zeros)
    const int kg   = (lane >> 4) * 8;
    const int mloc = tid >> 6;                  // local mtile 0..3
    const int mtile = blockIdx.x * 4 + mloc;
    const float* xp = x + (size_t)(mtile * 16 + c0) * HID + kg;

    const unsigned short* pH0 = &WP[0][c0][kg];
    const unsigned short* pH1 = &WP[0][c1][kg];
    const unsigned short* pL0 = &WP[1][c0][kg];
    const unsigned short* pL1 = &WP[1][c1][kg];

    f32x4 acc0 = {0.f, 0.f, 0.f, 0.f};
    f32x4 acc1 = {0.f, 0.f, 0.f, 0.f};

#define LDX(T)  (*reinterpret_cast<const float4*>(xp + 32 * (T)))
#define LDX4(T) (*reinterpret_cast<const float4*>(xp + 32 * (T) + 4))

#define XSTEP(Q0, Q1, T)                                                      \
    {                                                                         \
        const int LK = 32 * (T);                                              \
        union { unsigned u[4]; bf16x8 v; } H_, L_;                            \
        H_.u[0] = cvtpk(Q0.x, Q0.y);                                          \
        H_.u[1] = cvtpk(Q0.z, Q0.w);                                          \
        H_.u[2] = cvtpk(Q1.x, Q1.y);                                          \
        H_.u[3] = cvtpk(Q1.z, Q1.w);                                          \
        L_.u[0] = cvtpk(Q0.x - __uint_as_float(H_.u[0] << 16),                \
                        Q0.y - __uint_as_float(H_.u[0] & 0xFFFF0000u));       \
        L_.u[1] = cvtpk(Q0.z - __uint_as_float(H_.u[1] << 16),                \
                        Q0.w - __uint_as_float(H_.u[1] & 0xFFFF0000u));       \
        L_.u[2] = cvtpk(Q1.x - __uint_as_float(H_.u[2] << 16),                \
                        Q1.y - __uint_as_float(H_.u[2] & 0xFFFF0000u));       \
        L_.u[3] = cvtpk(Q1.z - __uint_as_float(H_.u[3] << 16),                \
                        Q1.w - __uint_as_float(H_.u[3] & 0xFFFF0000u));       \
        const bf16x8 bh0 = *reinterpret_cast<const bf16x8*>(pH0 + LK);        \
        const bf16x8 bh1 = *reinterpret_cast<const bf16x8*>(pH1 + LK);        \
        const bf16x8 bl0 = *reinterpret_cast<const bf16x8*>(pL0 + LK);        \
        const bf16x8 bl1 = *reinterpret_cast<const bf16x8*>(pL1 + LK);        \
        acc0 = __builtin_amdgcn_mfma_f32_16x16x32_bf16(H_.v, bh0, acc0, 0, 0, 0); \
        acc0 = __builtin_amdgcn_mfma_f32_16x16x32_bf16(H_.v, bl0, acc0, 0, 0, 0); \
        acc0 = __builtin_amdgcn_mfma_f32_16x16x32_bf16(L_.v, bh0, acc0, 0, 0, 0); \
        acc1 = __builtin_amdgcn_mfma_f32_16x16x32_bf16(H_.v, bh1, acc1, 0, 0, 0); \
        acc1 = __builtin_amdgcn_mfma_f32_16x16x32_bf16(H_.v, bl1, acc1, 0, 0, 0); \
        acc1 = __builtin_amdgcn_mfma_f32_16x16x32_bf16(L_.v, bh1, acc1, 0, 0, 0); \
    }

    // 4-deep rotation: qA..qD named pairs, 6KB/wave in flight at every stall
    float4 qA0 = LDX(0), qA1 = LDX4(0);
    float4 qB0 = LDX(1), qB1 = LDX4(1);
    float4 qC0 = LDX(2), qC1 = LDX4(2);
    float4 qD0 = LDX(3), qD1 = LDX4(3);

#pragma unroll
    for (int t = 0; t < 24; t += 4) {
        XSTEP(qA0, qA1, t)
        if (t + 4 < 24) { qA0 = LDX(t + 4); qA1 = LDX4(t + 4); }
        XSTEP(qB0, qB1, t + 1)
        if (t + 5 < 24) { qB0 = LDX(t + 5); qB1 = LDX4(t + 5); }
        XSTEP(qC0, qC1, t + 2)
        if (t + 6 < 24) { qC0 = LDX(t + 6); qC1 = LDX4(t + 6); }
        XSTEP(qD0, qD1, t + 3)
        if (t + 7 < 24) { qD0 = LDX(t + 7); qD1 = LDX4(t + 7); }
    }
#undef XSTEP
#undef LDX
#undef LDX4

    // ---- epilogue: global write + LDS scatter for the in-block scan ----
    const float bc  = bias[c0];
    const float b16 = bias[16];
    const int   rb  = mtile * 16 + (lane >> 4) * 4;
    const int   lr  = mloc * 16 + (lane >> 4) * 4;     // local row base
#pragma unroll
    for (int i = 0; i < 4; ++i) {
        const int row = rb + i;
        const float v0 = acc0[i] + bc;
        y[(size_t)row * NL + c0] = v0;
        em_s[lr + i][c0] = v0;
        if (c0 == 0) {
            const float v1 = acc1[i] + b16;
            y[(size_t)row * NL + 16] = v1;
            em_s[lr + i][16] = v1;
        }
    }
    __syncthreads();                            // em_s complete

    // ---- scan phase: waves 0,1 each run one 32-step segment ----
    const int widx = tid >> 6;
    if (widx >= 2) return;
    {
        const int l  = lane;
        const int b  = blockIdx.x >> 3;          // batch
        const int q8 = blockIdx.x & 7;
        const int sl = (q8 << 1) + widx;         // segment 0..15
        const int T0 = q8 << 6;                  // batch-step of local row 0

        int lenp = 0;
#pragma unroll
        for (int m = 0; m < 8; ++m) lenp += (mask[b * TT + l + 64 * m] != 0);
#pragma unroll
        for (int off = 32; off; off >>= 1) lenp += __shfl_down(lenp, off);
        const int len = __shfl(lenp, 0);

        const int tstart = (32 * sl > 1) ? 32 * sl : 1;
        int tend = 32 * sl + 32; if (tend > len) tend = len;
        const int trips = tend - tstart;

        const bool act = (l < 51);
        const int  i   = act ? (l / 3) : 0;
        const int  m3  = act ? (l - 3 * (l / 3)) : 0;
        const int  j0  = 6 * m3;

        if (act) {
#pragma unroll
            for (int jj = 0; jj < 6; ++jj)
                QT[widx][0][j0 + jj][i] = (i == j0 + jj) ? 1.f : 0.f;
        }

        float at[17];
#pragma unroll
        for (int k = 0; k < 17; ++k) at[k] = __expf(tr_[k * NL + i]);

        float psc = 1.f;
        int   Mi  = 0;
        float emv = (trips > 0) ? em_s[tstart - T0][i] : 0.f;
        int   t   = tstart;

#define QSTEPF(SRC, DST, TCUR)                                                \
    {                                                                         \
        const float e_ = __expf(emv) * psc;  psc = 1.f;                       \
        int ln_ = (TCUR) + 1 - T0; ln_ = (ln_ < 63) ? ln_ : 63;               \
        const float env_ = em_s[ln_][i];                                      \
        float o[6];                                                           \
        _Pragma("unroll")                                                     \
        for (int jj = 0; jj < 6; ++jj) {                                      \
            const float* qr = &QT[widx][SRC][j0 + jj][0];                     \
            const float4 a0 = *reinterpret_cast<const float4*>(qr);           \
            const float4 a1 = *reinterpret_cast<const float4*>(qr + 4);       \
            const float4 a2 = *reinterpret_cast<const float4*>(qr + 8);       \
            const float4 a3 = *reinterpret_cast<const float4*>(qr + 12);      \
            const float aL  = qr[16];                                         \
            float u0 = at[0] * a0.x, u1 = at[1] * a0.y;                       \
            float u2 = at[2] * a0.z, u3 = at[3] * a0.w;                       \
            u0 = fmaf(at[4],  a1.x, u0); u1 = fmaf(at[5],  a1.y, u1);         \
            u2 = fmaf(at[6],  a1.z, u2); u3 = fmaf(at[7],  a1.w, u3);         \
            u0 = fmaf(at[8],  a2.x, u0); u1 = fmaf(at[9],  a2.y, u1);         \
            u2 = fmaf(at[10], a2.z, u2); u3 = fmaf(at[11], a2.w, u3);         \
            u0 = fmaf(at[12], a3.x, u0); u1 = fmaf(at[13], a3.y, u1);         \
            u2 = fmaf(at[14], a3.z, u2); u3 = fmaf(at[15], a3.w, u3);         \
            u0 = fmaf(at[16], aL,   u0);                                      \
            o[jj] = (u0 + u1) + (u2 + u3);                                    \
        }                                                                     \
        if (act) {                                                            \
            _Pragma("unroll")                                                 \
            for (int jj = 0; jj < 6; ++jj)                                    \
                QT[widx][DST][j0 + jj][i] = e_ * o[jj];                       \
        }                                                                     \
        emv = env_;                                                           \
    }

        for (int pp = 0; pp < (trips >> 1); ++pp) {
            QSTEPF(0, 1, t)
            QSTEPF(1, 0, t + 1)
            t += 2;
            const float q00 = QT[widx][0][0][0];
            const int E = (int)((__float_as_uint(q00) >> 23) & 0xff) - 127;
            Mi += E;
            psc = __builtin_amdgcn_ldexpf(1.f, -E);
        }
        int sbuf = 0;
        if (trips > 0 && (trips & 1)) { QSTEPF(0, 1, t) sbuf = 1; }
#undef QSTEPF

        const int bs = b * SEG + sl;
        if (act) {
            float* dst = ws + (size_t)bs * QST + i * 20;
#pragma unroll
            for (int jj = 0; jj < 6; ++jj) {
                const int j = j0 + jj;
                if (j < 17) dst[j] = psc * QT[widx][sbuf][j][i];
            }
        }
        if (l == 0) ws[(size_t)bs * QST + 340] = (float)Mi;
    }
}

// ===========================================================================
// Kernel 2: combine — UNCHANGED from R12 (segment partition shift is
// transparent: ordered product of Q_0..Q_15 covers t=1..len-1 exactly).
// ===========================================================================
__device__ __forceinline__ float bcast(float v, int i) {
    return __uint_as_float(__builtin_amdgcn_readlane(__float_as_uint(v), i));
}

__global__ __launch_bounds__(64) void crf_combine_kernel(const float* __restrict__ emis,
                                                         const float* __restrict__ st_,
                                                         const float* __restrict__ en_,
                                                         const float* __restrict__ tr_,
                                                         const int* __restrict__ labels,
                                                         const int* __restrict__ mask,
                                                         const float* __restrict__ ws,
                                                         float* __restrict__ llh) {
    const int b = blockIdx.x;
    const int l = threadIdx.x;
    const float* eb = emis + (size_t)b * TT * NL;
    const int*   lb = labels + b * TT;

    int lenp = 0;
#pragma unroll
    for (int m = 0; m < 8; ++m) lenp += (mask[b * TT + l + 64 * m] != 0);
#pragma unroll
    for (int off = 32; off; off >>= 1) lenp += __shfl_down(lenp, off);
    const int len = __shfl(lenp, 0);

    float np = 0.f;
#pragma unroll
    for (int m = 0; m < 8; ++m) {
        const int t = l + 64 * m;
        int tag = lb[t]; if ((unsigned)tag >= NL) tag = 0;
        if (t < len) {
            if (t == 0) {
                np += st_[tag] + eb[tag];
            } else {
                int tp = lb[t - 1]; if ((unsigned)tp >= NL) tp = 0;
                np += tr_[tp * NL + tag] + eb[t * NL + tag];
            }
            if (t == len - 1) np += en_[tag];
        }
    }
#pragma unroll
    for (int off = 32; off; off >>= 1) np += __shfl_down(np, off);
    const float num = __shfl(np, 0);

    const bool act = (l < NL);
    const int  j   = act ? l : 0;

    float p  = act ? __expf(st_[j] + eb[j]) : 0.f;
    int   Mi = 0;

    for (int s = 0; s < SEG; ++s) {
        const float* qs = ws + (size_t)(b * SEG + s) * QST;
        const float* qr = qs + j * 20;
        const float4 a0 = *reinterpret_cast<const float4*>(qr);
        const float4 a1 = *reinterpret_cast<const float4*>(qr + 4);
        const float4 a2 = *reinterpret_cast<const float4*>(qr + 8);
        const float4 a3 = *reinterpret_cast<const float4*>(qr + 12);
        const float  aL = qr[16];
        const float  Msc = qs[340];

        float u0 = a0.x * bcast(p, 0),  u1 = a0.y * bcast(p, 1);
        float u2 = a0.z * bcast(p, 2),  u3 = a0.w * bcast(p, 3);
        u0 = fmaf(a1.x, bcast(p, 4),  u0); u1 = fmaf(a1.y, bcast(p, 5),  u1);
        u2 = fmaf(a1.z, bcast(p, 6),  u2); u3 = fmaf(a1.w, bcast(p, 7),  u3);
        u0 = fmaf(a2.x, bcast(p, 8),  u0); u1 = fmaf(a2.y, bcast(p, 9),  u1);
        u2 = fmaf(a2.z, bcast(p, 10), u2); u3 = fmaf(a2.w, bcast(p, 11), u3);
        u0 = fmaf(a3.x, bcast(p, 12), u0); u1 = fmaf(a3.y, bcast(p, 13), u1);
        u2 = fmaf(a3.z, bcast(p, 14), u2); u3 = fmaf(a3.w, bcast(p, 15), u3);
        u0 = fmaf(aL,   bcast(p, 16), u0);
        p = act ? ((u0 + u1) + (u2 + u3)) : 0.f;
        Mi += (int)Msc;

        const unsigned pb = (unsigned)__builtin_amdgcn_readlane((int)__float_as_uint(p), 0);
        const int e = (int)((pb >> 23) & 0xff) - 127;
        Mi += e;
        p = __builtin_amdgcn_ldexpf(p, -e);
    }

    float v = act ? p * __expf(en_[j]) : 0.f;
#pragma unroll
    for (int off = 32; off; off >>= 1) v += __shfl_down(v, off);

    if (l == 0) {
        const float denom = (float)Mi * 0.6931471805599453f + __logf(v);
        llh[b] = num - denom;
    }
}

// ===========================================================================
// Kernel 3: loss = -mean(llh)
// ===========================================================================
__global__ __launch_bounds__(64) void loss_kernel(const float* __restrict__ llh,
                                                  float* __restrict__ loss) {
    float v = llh[threadIdx.x];
#pragma unroll
    for (int off = 32; off; off >>= 1) v += __shfl_down(v, off);
    if (threadIdx.x == 0) loss[0] = -(v * (1.0f / BB));
}

// ===========================================================================
extern "C" void kernel_launch(void* const* d_in, const int* in_sizes, int n_in,
                              void* d_out, int out_size, void* d_ws, size_t ws_size,
                              hipStream_t stream) {
    const float* outputs = (const float*)d_in[0];
    const float* fc_w    = (const float*)d_in[1];
    const float* fc_b    = (const float*)d_in[2];
    const float* start_t = (const float*)d_in[3];
    const float* end_t   = (const float*)d_in[4];
    const float* trans   = (const float*)d_in[5];
    const int*   labels  = (const int*)d_in[6];
    const int*   mask    = (const int*)d_in[7];

    float* emis = (float*)d_out;
    float* loss = emis + (size_t)BB * TT * NL;
    float* ws   = (float*)d_ws;
    float* llh  = ws + (size_t)BB * SEG * QST;

    emis_scan_kernel<<<(BB * TT) / 64, 256, 0, stream>>>(outputs, fc_w, fc_b,
                                                         mask, trans, emis, ws);
    crf_combine_kernel<<<BB, 64, 0, stream>>>(emis, start_t, end_t, trans,
                                              labels, mask, ws, llh);
    loss_kernel<<<1, 64, 0, stream>>>(llh, loss);
}